// Round 1
// 1733.012 us; speedup vs baseline: 1.9635x; 1.9635x over previous
//
#include <hip/hip_runtime.h>

#define ALPHA 0.35f
#define BQ 1024
#define DIM 384
#define NC 131072
#define TOPK 16

#define QT 128              // queries per block
#define NQT (BQ / QT)       // 8
#define CH 512              // candidates per chunk
#define NCH (NC / CH)       // 256
#define SUBC 64             // candidates per subtile (128 interleaved crows)
#define NSUB (CH / SUBC)    // 8
#define BK 64               // bf16 k-slice
#define NKI (DIM / BK)      // 6
#define ASTR 72             // LDS row stride (bf16 elems): 144B, 16B-aligned, 2-way max

typedef short bf16x8 __attribute__((ext_vector_type(8)));
typedef float floatx4 __attribute__((ext_vector_type(4)));
typedef unsigned long long ull;
typedef unsigned int u32;

// pack 2 fp32 -> 2 bf16 (truncation) in one v_perm_b32.
static __device__ __forceinline__ unsigned pk2(float a, float b) {
  unsigned ua = __builtin_bit_cast(unsigned, a);
  unsigned ub = __builtin_bit_cast(unsigned, b);
  return __builtin_amdgcn_perm(ub, ua, 0x07060302u);
}

// stage 32 fp32 -> 32 bf16 (64B) into LDS
static __device__ __forceinline__ void stage_half(const float* __restrict__ src,
                                                  ushort* __restrict__ dst) {
  const float4* p = reinterpret_cast<const float4*>(src);
  float4 v0 = p[0], v1 = p[1], v2 = p[2], v3 = p[3];
  float4 v4 = p[4], v5 = p[5], v6 = p[6], v7 = p[7];
  uint4* q = reinterpret_cast<uint4*>(dst);
  q[0] = make_uint4(pk2(v0.x, v0.y), pk2(v0.z, v0.w), pk2(v1.x, v1.y), pk2(v1.z, v1.w));
  q[1] = make_uint4(pk2(v2.x, v2.y), pk2(v2.z, v2.w), pk2(v3.x, v3.y), pk2(v3.z, v3.w));
  q[2] = make_uint4(pk2(v4.x, v4.y), pk2(v4.z, v4.w), pk2(v5.x, v5.y), pk2(v5.z, v5.w));
  q[3] = make_uint4(pk2(v6.x, v6.y), pk2(v6.z, v6.w), pk2(v7.x, v7.y), pk2(v7.z, v7.w));
}

// ---- register-resident bitonic top-16 primitives on packed u64 keys ----
// key = (orderable(value) << 32) | ~idx  -> single u64 compare gives
// (value desc, idx asc) ordering exactly.
static __device__ __forceinline__ void ce_asc(ull& a, ull& b) {
  ull lo = b < a ? b : a;
  ull hi = b < a ? a : b;
  a = lo; b = hi;
}
static __device__ __forceinline__ void ce_desc(ull& a, ull& b) {
  ull lo = b < a ? b : a;
  ull hi = b < a ? a : b;
  a = hi; b = lo;
}
// full bitonic sort of 16 keys, ascending (80 compare-exchanges, unrolled)
static __device__ __forceinline__ void sort16_asc(ull* B) {
  #pragma unroll
  for (int k = 2; k <= 16; k <<= 1) {
    #pragma unroll
    for (int j = k >> 1; j > 0; j >>= 1) {
      #pragma unroll
      for (int i = 0; i < 16; i++) {
        int l = i ^ j;
        if (l > i) {
          if ((i & k) == 0) ce_asc(B[i], B[l]);
          else              ce_desc(B[i], B[l]);
        }
      }
    }
  }
}
// H is bitonic -> sort descending (bitonic merge, 32 CEs)
static __device__ __forceinline__ void merge_desc16(ull* H) {
  #pragma unroll
  for (int j = 8; j > 0; j >>= 1) {
    #pragma unroll
    for (int i = 0; i < 16; i++) {
      int l = i ^ j;
      if (l > i) ce_desc(H[i], H[l]);
    }
  }
}

// ---------------- kernel 1: normalize queries (fp32, exact ref math) ----------------
__global__ __launch_bounds__(384) void qnorm_kernel(const float* __restrict__ q,
                                                    float* __restrict__ qn) {
  const int b = blockIdx.x;
  const int t = threadIdx.x;
  float v = q[b * DIM + t];
  float s = v * v;
  #pragma unroll
  for (int m = 32; m; m >>= 1) s += __shfl_xor(s, m);
  __shared__ float ws[6];
  if ((t & 63) == 0) ws[t >> 6] = s;
  __syncthreads();
  float tot = ws[0] + ws[1] + ws[2] + ws[3] + ws[4] + ws[5];
  float n = fmaxf(sqrtf(tot), 1e-12f);
  qn[b * DIM + t] = v / n;
}

// ---------------- kernel 2: inverse row norms of e and d (exact ref math) ----------------
__global__ __launch_bounds__(256) void rownorm_kernel(const float* __restrict__ e,
                                                      const float* __restrict__ d,
                                                      float* __restrict__ inv_e,
                                                      float* __restrict__ inv_d) {
  const int wid = threadIdx.x >> 6, lane = threadIdx.x & 63;
  const int row = blockIdx.x * 4 + wid;
  const float* src = blockIdx.y ? d : e;
  const float* p = src + (size_t)row * DIM;
  float s = 0.f;
  #pragma unroll
  for (int j = 0; j < 6; j++) { float v = p[j * 64 + lane]; s += v * v; }
  #pragma unroll
  for (int m = 32; m; m >>= 1) s += __shfl_xor(s, m);
  if (lane == 0) {
    float n = fmaxf(sqrtf(s), 1e-12f);
    (blockIdx.y ? inv_d : inv_e)[row] = 1.0f / n;
  }
}

// ---------------- kernel 3: bf16 MFMA approx scores + per-chunk top-16 ----------------
// grid (NQT, NCH): qt fast so the 8 q-tile blocks of one chunk slab co-run (L2/L3 reuse).
// block 256. crow 2i -> e_i, crow 2i+1 -> d_i.
// Selection: per-thread register bitonic top-16 over packed u64 keys, 2 threads/query
// (uniform, no divergence, no LDS heap -> kills the 3e8 bank-conflict cycles).
__global__ __launch_bounds__(256, 3) void score_kernel(
    const float* __restrict__ e, const float* __restrict__ d,
    const float* __restrict__ qn, const float* __restrict__ inv_e,
    const float* __restrict__ inv_d, float* __restrict__ cand_vals,
    int* __restrict__ cand_idx) {
  // LDS: [A 128x72 bf16 | B 128x72 bf16] (36864B), aliased by scores 128x65 fp32
  //      and by the final key-exchange buffer. 36864B total.
  __shared__ __align__(16) char smem[36864];
  ushort* As = (ushort*)smem;
  ushort* Bs = (ushort*)(smem + 18432);
  float*  sc = (float*)smem;                 // stride 65

  const int t = threadIdx.x;
  const int qt = blockIdx.x, ch = blockIdx.y;
  const int q0 = qt * QT;
  const int c0 = ch * CH;
  const int lane = t & 63, wave = t >> 6;
  const int wy = wave >> 1, wx = wave & 1;
  const int mrow = lane & 15, quad = lane >> 4;

  // selection mapping: 2 threads per query, halves of each sub's 64 candidates
  const int q = t & 127;       // owned query (row of sc)
  const int h = t >> 7;        // half: cols h*32 .. h*32+31

  // staging mapping: thread t stages half-row (32 floats) of A row srow and B crow srow
  const int srow = t >> 1, shalf = t & 1;
  const float* qsrc = qn + (size_t)(q0 + srow) * DIM + shalf * 32;
  const float* bsel = (srow & 1) ? d : e;

  ull H[16];                   // running top-16 keys, sorted descending
  #pragma unroll
  for (int i = 0; i < 16; i++) H[i] = 0ull;   // key 0 < any real score key

  for (int sub = 0; sub < NSUB; sub++) {
    const int cb = c0 + sub * SUBC;
    const float* bsrc = bsel + (size_t)(cb + (srow >> 1)) * DIM + shalf * 32;
    floatx4 acc[4][4];
    #pragma unroll
    for (int i = 0; i < 4; i++)
      #pragma unroll
      for (int j = 0; j < 4; j++) acc[i][j] = (floatx4)0.f;

    for (int ki = 0; ki < NKI; ki++) {
      const int kb = ki * BK;
      __syncthreads();  // tiles/scores free
      stage_half(qsrc + kb, &As[srow * ASTR + shalf * 32]);
      stage_half(bsrc + kb, &Bs[srow * ASTR + shalf * 32]);
      __syncthreads();
      #pragma unroll
      for (int ks = 0; ks < 2; ks++) {
        bf16x8 af[4], bf[4];
        #pragma unroll
        for (int i = 0; i < 4; i++)
          af[i] = *reinterpret_cast<const bf16x8*>(&As[(wy * 64 + i * 16 + mrow) * ASTR + ks * 32 + quad * 8]);
        #pragma unroll
        for (int j = 0; j < 4; j++)
          bf[j] = *reinterpret_cast<const bf16x8*>(&Bs[(wx * 64 + j * 16 + mrow) * ASTR + ks * 32 + quad * 8]);
        #pragma unroll
        for (int i = 0; i < 4; i++)
          #pragma unroll
          for (int j = 0; j < 4; j++)
            acc[i][j] = __builtin_amdgcn_mfma_f32_16x16x32_bf16(af[i], bf[j], acc[i][j], 0, 0, 0);
      }
    }
    __syncthreads();  // MFMA frag reads done -> scores may overwrite tiles
    // epilogue: C layout col=lane&15 (crow), row=quad*4+reg (q). even col=primal, odd=dual.
    {
      const int col = lane & 15;
      #pragma unroll
      for (int j = 0; j < 4; j++) {
        const int candl = wx * 32 + j * 8 + (col >> 1);
        const int cg = cb + candl;
        const float ie = inv_e[cg];
        const float id = inv_d[cg];
        #pragma unroll
        for (int i = 0; i < 4; i++) {
          #pragma unroll
          for (int r = 0; r < 4; r++) {
            float v = acc[i][j][r];
            float p = __shfl_xor(v, 1);
            if (!(col & 1)) {
              float s = v * ie + ALPHA * fmaxf(p * id, 0.f);
              sc[(wy * 64 + i * 16 + quad * 4 + r) * 65 + candl] = s;
            }
          }
        }
      }
    }
    __syncthreads();
    // ---- uniform register top-16 merge: 2 batches of 16 candidates ----
    #pragma unroll
    for (int b = 0; b < 2; b++) {
      ull Bk[16];
      #pragma unroll
      for (int j = 0; j < 16; j++) {
        const int c = h * 32 + b * 16 + j;
        float s = sc[q * 65 + c];
        u32 u = __builtin_bit_cast(u32, s);
        u32 m = (u & 0x80000000u) ? ~u : (u | 0x80000000u);   // orderable fp32
        Bk[j] = ((ull)m << 32) | (u32)~(u32)(cb + c);
      }
      sort16_asc(Bk);
      // half-clean: [H desc ; Bk asc] is bitonic; max-half = top-16 of union (bitonic)
      #pragma unroll
      for (int i = 0; i < 16; i++) H[i] = H[i] >= Bk[i] ? H[i] : Bk[i];
      merge_desc16(H);
    }
    // next iteration's first __syncthreads protects sc before restaging
  }

  // ---- merge the two half-stream top-16s per query, emit chunk top-16 ----
  __syncthreads();
  u32* scu = (u32*)smem;
  if (h == 1) {
    #pragma unroll
    for (int i = 0; i < 16; i++) {
      scu[q * 65 + i]      = (u32)(H[i] >> 32);
      scu[q * 65 + 16 + i] = (u32)H[i];
    }
  }
  __syncthreads();
  if (h == 0) {
    #pragma unroll
    for (int i = 0; i < 16; i++) {
      ull o = ((ull)scu[q * 65 + (15 - i)] << 32) | scu[q * 65 + 16 + (15 - i)];  // reversed -> asc
      H[i] = H[i] >= o ? H[i] : o;
    }
    merge_desc16(H);
    const int qg = q0 + q;
    const size_t base = ((size_t)ch * BQ + qg) * TOPK;
    #pragma unroll
    for (int i = 0; i < 16; i++) {
      u32 m = (u32)(H[i] >> 32);
      u32 u = (m & 0x80000000u) ? (m & 0x7fffffffu) : ~m;     // un-orderable
      cand_vals[base + i] = __builtin_bit_cast(float, u);
      cand_idx[base + i] = (int)~(u32)H[i];
    }
  }
}

// ---------------- kernel 4: merge 256 chunk-lists -> approx top-32 -> fp32 rescore -> top-16 ----------------
#define POOL (NCH * TOPK)   // 4096
#define MSEL 32
__global__ __launch_bounds__(256) void merge_rescore_kernel(
    const float* __restrict__ cand_vals, const int* __restrict__ cand_idx,
    const float* __restrict__ qn, const float* __restrict__ e,
    const float* __restrict__ d, const float* __restrict__ inv_e,
    const float* __restrict__ inv_d, float* __restrict__ out) {
  __shared__ float mv[POOL];
  __shared__ int   mi[POOL];
  __shared__ float qf[DIM];
  __shared__ float wrv[4]; __shared__ int wri[4]; __shared__ int wrp[4];
  __shared__ float selv[MSEL]; __shared__ int seli[MSEL];
  __shared__ float fv[MSEL]; __shared__ int fi[MSEL];

  const int q = blockIdx.x, t = threadIdx.x;
  const int lane = t & 63, wave = t >> 6;

  #pragma unroll
  for (int j = 0; j < POOL / 256; j++) {
    int el = t + 256 * j;
    mv[el] = cand_vals[((size_t)(el >> 4) * BQ + q) * TOPK + (el & 15)];
    mi[el] = cand_idx[((size_t)(el >> 4) * BQ + q) * TOPK + (el & 15)];
  }
  if (t < 128) { qf[t] = qn[q * DIM + t]; qf[t + 128] = qn[q * DIM + t + 128]; qf[t + 256] = qn[q * DIM + t + 256]; }
  __syncthreads();

  // select approx top-32 (value desc, index asc)
  for (int pass = 0; pass < MSEL; pass++) {
    float bv = -INFINITY; int bi = 0x7fffffff, bp = 0;
    #pragma unroll
    for (int j = 0; j < POOL / 256; j++) {
      int el = t + 256 * j;
      float v = mv[el]; int ix = mi[el];
      if (v > bv || (v == bv && ix < bi)) { bv = v; bi = ix; bp = el; }
    }
    #pragma unroll
    for (int off = 1; off < 64; off <<= 1) {
      float ov = __shfl_xor(bv, off); int oi = __shfl_xor(bi, off); int op = __shfl_xor(bp, off);
      if (ov > bv || (ov == bv && oi < bi)) { bv = ov; bi = oi; bp = op; }
    }
    if (lane == 0) { wrv[wave] = bv; wri[wave] = bi; wrp[wave] = bp; }
    __syncthreads();
    if (t == 0) {
      float xv = wrv[0]; int xi = wri[0], xp = wrp[0];
      #pragma unroll
      for (int w = 1; w < 4; w++) {
        if (wrv[w] > xv || (wrv[w] == xv && wri[w] < xi)) { xv = wrv[w]; xi = wri[w]; xp = wrp[w]; }
      }
      selv[pass] = xv; seli[pass] = xi;
      mv[xp] = -INFINITY; mi[xp] = 0x7fffffff;
    }
    __syncthreads();
  }

  // exact fp32 rescore of the 32 candidates (same math as reference)
  for (int c = wave; c < MSEL; c += 4) {
    int idx = seli[c];
    const float* er = e + (size_t)idx * DIM;
    const float* dr = d + (size_t)idx * DIM;
    float se = 0.f, sd = 0.f;
    #pragma unroll
    for (int j = 0; j < 6; j++) {
      float qv = qf[j * 64 + lane];
      se += qv * er[j * 64 + lane];
      sd += qv * dr[j * 64 + lane];
    }
    #pragma unroll
    for (int off = 32; off; off >>= 1) { se += __shfl_xor(se, off); sd += __shfl_xor(sd, off); }
    if (lane == 0) {
      fv[c] = se * inv_e[idx] + ALPHA * fmaxf(sd * inv_d[idx], 0.f);
      fi[c] = idx;
    }
  }
  __syncthreads();

  // final exact top-16 (value desc, index asc), serial on t==0
  if (t == 0) {
    unsigned used = 0u;
    for (int p = 0; p < TOPK; p++) {
      float bv = -INFINITY; int bi = 0x7fffffff, bp = 0;
      for (int c = 0; c < MSEL; c++) {
        if (used & (1u << c)) continue;
        float v = fv[c]; int ix = fi[c];
        if (v > bv || (v == bv && ix < bi)) { bv = v; bi = ix; bp = c; }
      }
      used |= (1u << bp);
      out[q * TOPK + p] = bv;
      out[BQ * TOPK + q * TOPK + p] = (float)bi;
    }
  }
}

extern "C" void kernel_launch(void* const* d_in, const int* in_sizes, int n_in,
                              void* d_out, int out_size, void* d_ws, size_t ws_size,
                              hipStream_t stream) {
  const float* q = (const float*)d_in[0];
  const float* e = (const float*)d_in[1];
  const float* d = (const float*)d_in[2];

  float* ws = (float*)d_ws;
  float* qn        = ws;                                   // 1024*384
  float* inv_e     = qn + BQ * DIM;                        // 131072
  float* inv_d     = inv_e + NC;                           // 131072
  float* cand_vals = inv_d + NC;                           // 256*1024*16
  int*   cand_idx  = (int*)(cand_vals + (size_t)NCH * BQ * TOPK);
  float* out = (float*)d_out;

  qnorm_kernel<<<BQ, 384, 0, stream>>>(q, qn);
  rownorm_kernel<<<dim3(NC / 4, 2), 256, 0, stream>>>(e, d, inv_e, inv_d);
  score_kernel<<<dim3(NQT, NCH), 256, 0, stream>>>(e, d, qn, inv_e, inv_d, cand_vals, cand_idx);
  merge_rescore_kernel<<<BQ, 256, 0, stream>>>(cand_vals, cand_idx, qn, e, d, inv_e, inv_d, out);
}

// Round 2
// 1598.471 us; speedup vs baseline: 2.1287x; 1.0842x over previous
//
#include <hip/hip_runtime.h>

#define ALPHA 0.35f
#define BQ 1024
#define DIM 384
#define NC 131072
#define TOPK 16

#define QT 128              // queries per block
#define NQT (BQ / QT)       // 8
#define CH 512              // candidates per chunk
#define NCH (NC / CH)       // 256
#define SUBC 64             // candidates per subtile (128 interleaved crows)
#define NSUB (CH / SUBC)    // 8
#define BK 64               // bf16 k-slice
#define NKI (DIM / BK)      // 6
#define NROUND (NSUB * NKI) // 48

typedef short bf16x8 __attribute__((ext_vector_type(8)));
typedef float floatx4 __attribute__((ext_vector_type(4)));
typedef unsigned long long ull;
typedef unsigned int u32;

#define AS1 __attribute__((address_space(1)))
#define AS3 __attribute__((address_space(3)))

// pack 2 fp32 -> 2 bf16 (truncation) in one v_perm_b32.
static __device__ __forceinline__ unsigned pk2(float a, float b) {
  unsigned ua = __builtin_bit_cast(unsigned, a);
  unsigned ub = __builtin_bit_cast(unsigned, b);
  return __builtin_amdgcn_perm(ub, ua, 0x07060302u);
}

// async global->LDS 16B DMA. lds ptr must be wave-uniform (HW adds lane*16).
static __device__ __forceinline__ void gl16(const char* g, const char* l) {
  __builtin_amdgcn_global_load_lds((const AS1 unsigned int*)(unsigned long long)g,
                                   (AS3 unsigned int*)(unsigned long long)l, 16, 0, 0);
}

// raw barrier with compiler memory fence (no vmcnt(0) drain like __syncthreads)
static __device__ __forceinline__ void bar() {
  asm volatile("" ::: "memory");
  __builtin_amdgcn_s_barrier();
  asm volatile("" ::: "memory");
}

// ---- register-resident bitonic top-16 primitives on packed u64 keys ----
static __device__ __forceinline__ void ce_asc(ull& a, ull& b) {
  ull lo = b < a ? b : a;
  ull hi = b < a ? a : b;
  a = lo; b = hi;
}
static __device__ __forceinline__ void ce_desc(ull& a, ull& b) {
  ull lo = b < a ? b : a;
  ull hi = b < a ? a : b;
  a = hi; b = lo;
}
static __device__ __forceinline__ void sort16_asc(ull* B) {
  #pragma unroll
  for (int k = 2; k <= 16; k <<= 1) {
    #pragma unroll
    for (int j = k >> 1; j > 0; j >>= 1) {
      #pragma unroll
      for (int i = 0; i < 16; i++) {
        int l = i ^ j;
        if (l > i) {
          if ((i & k) == 0) ce_asc(B[i], B[l]);
          else              ce_desc(B[i], B[l]);
        }
      }
    }
  }
}
static __device__ __forceinline__ void merge_desc16(ull* H) {
  #pragma unroll
  for (int j = 8; j > 0; j >>= 1) {
    #pragma unroll
    for (int i = 0; i < 16; i++) {
      int l = i ^ j;
      if (l > i) ce_desc(H[i], H[l]);
    }
  }
}

// ---------------- kernel 1: normalize queries + bf16 copy ----------------
__global__ __launch_bounds__(384) void qnorm_kernel(const float* __restrict__ q,
                                                    float* __restrict__ qn,
                                                    ushort* __restrict__ qn16) {
  const int b = blockIdx.x;
  const int t = threadIdx.x;
  float v = q[b * DIM + t];
  float s = v * v;
  #pragma unroll
  for (int m = 32; m; m >>= 1) s += __shfl_xor(s, m);
  __shared__ float ws[6];
  if ((t & 63) == 0) ws[t >> 6] = s;
  __syncthreads();
  float tot = ws[0] + ws[1] + ws[2] + ws[3] + ws[4] + ws[5];
  float n = fmaxf(sqrtf(tot), 1e-12f);
  float vn = v / n;
  qn[b * DIM + t] = vn;
  float vn1 = __shfl_down(vn, 1);
  if (!(t & 1)) ((u32*)qn16)[b * (DIM / 2) + (t >> 1)] = pk2(vn, vn1);
}

// ---------------- kernel 2: row norms (bitwise-identical order) + interleaved bf16 copy ----------------
// ed16 row 2i = e_i, row 2i+1 = d_i  (bf16 truncation, same pk2 as before)
__global__ __launch_bounds__(256) void convert_kernel(const float* __restrict__ e,
                                                      const float* __restrict__ d,
                                                      float* __restrict__ inv_e,
                                                      float* __restrict__ inv_d,
                                                      ushort* __restrict__ ed16) {
  const int wid = threadIdx.x >> 6, lane = threadIdx.x & 63;
  const int g = blockIdx.x * 4 + wid;      // global interleaved row
  const int cube = g >> 1, sel = g & 1;
  const float* p = (sel ? d : e) + (size_t)cube * DIM;
  float s = 0.f;
  #pragma unroll
  for (int j = 0; j < 6; j++) { float v = p[j * 64 + lane]; s += v * v; }  // exact old order
  #pragma unroll
  for (int m = 32; m; m >>= 1) s += __shfl_xor(s, m);
  if (lane == 0) {
    float n = fmaxf(sqrtf(s), 1e-12f);
    (sel ? inv_d : inv_e)[cube] = 1.0f / n;
  }
  u32* dst = (u32*)(ed16 + (size_t)g * DIM);
  #pragma unroll
  for (int j = 0; j < 3; j++) {
    float2 w = *(const float2*)(p + j * 128 + 2 * lane);
    dst[j * 64 + lane] = pk2(w.x, w.y);
  }
}

// ---------------- kernel 3: bf16 MFMA scores + per-chunk top-16 ----------------
// 1D grid 2048 with XCD affinity: all 8 q-tile blocks of a chunk on one XCD (L2 reuse).
// Staging: global_load_lds 16B, double-buffered, counted vmcnt(8) pipeline, raw barriers.
// LDS 64KB = [A0 16K][B0 16K][A1 16K][B1 16K]; score buffer aliases [A1 B1].
// XOR swizzle (slot ^= row&7, 16B slots) via pre-swizzled global source + swizzled reads.
__global__ __launch_bounds__(256, 2) void score_kernel(
    const ushort* __restrict__ ed16, const ushort* __restrict__ qn16,
    const float* __restrict__ inv_e, const float* __restrict__ inv_d,
    float* __restrict__ cand_vals, int* __restrict__ cand_idx) {
  __shared__ __align__(16) char smem[65536];

  const int t = threadIdx.x;
  const int bid = blockIdx.x;
  const int x8 = bid & 7, jj8 = bid >> 3;
  const int ch = x8 + 8 * (jj8 >> 3);   // chunk -> XCD x8
  const int qt = jj8 & 7;
  const int q0 = qt * QT;
  const int c0 = ch * CH;

  const int lane = t & 63, wave = t >> 6;
  const int wy = wave >> 1, wx = wave & 1;
  const int mrow = lane & 15, quad = lane >> 4;

  // selection mapping: 2 threads per query
  const int q = t & 127;
  const int h = t >> 7;

  // staging per-thread constants (row within 32-row quarter = wave*8 + lane>>3)
  const int sr8 = lane >> 3, ss = lane & 7;
  u32 offRow[4];
  #pragma unroll
  for (int k = 0; k < 4; k++) {
    int row = k * 32 + wave * 8 + sr8;                  // row & 7 == sr8
    offRow[k] = (u32)row * 768u + (u32)((ss ^ sr8) * 16);
  }
  const u32 ldsW = (u32)wave * 1024u;

  // frag read offsets (byte), swizzled
  u32 aoff[4], boff[4], sks[2];
  #pragma unroll
  for (int i = 0; i < 4; i++) aoff[i] = (u32)(wy * 64 + i * 16 + mrow) * 128u;
  #pragma unroll
  for (int j = 0; j < 4; j++) boff[j] = (u32)(wx * 64 + j * 16 + mrow) * 128u;
  #pragma unroll
  for (int ks = 0; ks < 2; ks++) sks[ks] = (u32)(((ks * 4 + quad) ^ (mrow & 7)) * 16);

  const char* qbase = (const char*)qn16 + (size_t)q0 * 768;
  const char* ebase = (const char*)ed16 + (size_t)(c0 * 2) * 768;

  auto STAGE = [&](int buf, int ssub, int ski) {
    const char* aS = qbase + (size_t)ski * 128;
    const char* bS = ebase + (size_t)(ssub * 128) * 768 + (size_t)ski * 128;
    const char* lb = smem + (u32)buf * 32768u + ldsW;
    #pragma unroll
    for (int k = 0; k < 4; k++) {
      gl16(aS + offRow[k], lb + k * 4096u);
      gl16(bS + offRow[k], lb + 16384u + k * 4096u);
    }
  };

  float* sc = (float*)(smem + 32768);   // 128 rows x 64 words, XOR(q&31) swizzled

  ull H[16];
  #pragma unroll
  for (int i = 0; i < 16; i++) H[i] = 0ull;

  STAGE(0, 0, 0);   // prologue

  for (int sub = 0; sub < NSUB; sub++) {
    const int cb = c0 + sub * SUBC;
    float ie[4], id[4];
    #pragma unroll
    for (int j = 0; j < 4; j++) {
      int cg = cb + wx * 32 + j * 8 + (mrow >> 1);
      ie[j] = inv_e[cg]; id[j] = inv_d[cg];
    }
    floatx4 acc[4][4];
    #pragma unroll
    for (int i = 0; i < 4; i++)
      #pragma unroll
      for (int j = 0; j < 4; j++) acc[i][j] = (floatx4)0.f;

    #pragma unroll
    for (int ki = 0; ki < NKI; ki++) {
      const int rr = sub * NKI + ki;      // buffer = rr&1 (ki&1 since NKI even per sub start)
      // issue next stage, keep it in flight across the barrier (counted vmcnt)
      if (!(sub == NSUB - 1 && ki == NKI - 1)) {
        const int nsub = (ki == NKI - 1) ? sub + 1 : sub;
        const int nki  = (ki == NKI - 1) ? 0 : ki + 1;
        STAGE((rr + 1) & 1, nsub, nki);
        asm volatile("s_waitcnt vmcnt(8)" ::: "memory");   // current tile landed
      } else {
        asm volatile("s_waitcnt vmcnt(0)" ::: "memory");
      }
      bar();
      const char* Ab = smem + (u32)(rr & 1) * 32768u;
      const char* Bb = Ab + 16384;
      #pragma unroll
      for (int ks = 0; ks < 2; ks++) {
        bf16x8 af[4], bf[4];
        #pragma unroll
        for (int i = 0; i < 4; i++)
          af[i] = *reinterpret_cast<const bf16x8*>(Ab + aoff[i] + sks[ks]);
        #pragma unroll
        for (int j = 0; j < 4; j++)
          bf[j] = *reinterpret_cast<const bf16x8*>(Bb + boff[j] + sks[ks]);
        __builtin_amdgcn_s_setprio(1);
        #pragma unroll
        for (int i = 0; i < 4; i++)
          #pragma unroll
          for (int j = 0; j < 4; j++)
            acc[i][j] = __builtin_amdgcn_mfma_f32_16x16x32_bf16(af[i], bf[j], acc[i][j], 0, 0, 0);
        __builtin_amdgcn_s_setprio(0);
      }
      bar();   // all waves' frag reads of this buffer complete
    }

    // epilogue: C layout col=lane&15 (crow), row=quad*4+reg (q). even col=primal, odd=dual.
    // sc aliases [A1 B1] (last round's buffer = buf1); prefetch in flight targets buf0.
    {
      const int col = lane & 15;
      #pragma unroll
      for (int j = 0; j < 4; j++) {
        const int candl = wx * 32 + j * 8 + (col >> 1);
        #pragma unroll
        for (int i = 0; i < 4; i++) {
          #pragma unroll
          for (int r = 0; r < 4; r++) {
            float v = acc[i][j][r];
            float p = __shfl_xor(v, 1);
            if (!(col & 1)) {
              const int qrow = wy * 64 + i * 16 + quad * 4 + r;
              float s = v * ie[j] + ALPHA * fmaxf(p * id[j], 0.f);
              sc[qrow * 64 + (candl ^ (qrow & 31))] = s;
            }
          }
        }
      }
    }
    __syncthreads();
    // ---- uniform register top-16 merge: 2 batches of 16 candidates ----
    #pragma unroll
    for (int b = 0; b < 2; b++) {
      ull Bk[16];
      #pragma unroll
      for (int j = 0; j < 16; j++) {
        const int c = h * 32 + b * 16 + j;
        float s = sc[q * 64 + (c ^ (q & 31))];
        u32 u = __builtin_bit_cast(u32, s);
        u32 m = (u & 0x80000000u) ? ~u : (u | 0x80000000u);   // orderable fp32
        Bk[j] = ((ull)m << 32) | (u32)~(u32)(cb + c);
      }
      sort16_asc(Bk);
      #pragma unroll
      for (int i = 0; i < 16; i++) H[i] = H[i] >= Bk[i] ? H[i] : Bk[i];
      merge_desc16(H);
    }
    __syncthreads();   // selection reads done before next sub stages into buf1 (= sc)
  }

  // ---- merge the two half-stream top-16s per query, emit chunk top-16 ----
  u32* scu = (u32*)(smem + 32768);
  if (h == 1) {
    #pragma unroll
    for (int i = 0; i < 16; i++) {
      scu[q * 64 + (i ^ (q & 31))]        = (u32)(H[i] >> 32);
      scu[q * 64 + ((16 + i) ^ (q & 31))] = (u32)H[i];
    }
  }
  __syncthreads();
  if (h == 0) {
    #pragma unroll
    for (int i = 0; i < 16; i++) {
      ull o = ((ull)scu[q * 64 + ((15 - i) ^ (q & 31))] << 32) |
              scu[q * 64 + ((31 - i) ^ (q & 31))];            // reversed -> asc
      H[i] = H[i] >= o ? H[i] : o;
    }
    merge_desc16(H);
    const int qg = q0 + q;
    const size_t base = ((size_t)ch * BQ + qg) * TOPK;
    #pragma unroll
    for (int i = 0; i < 16; i++) {
      u32 m = (u32)(H[i] >> 32);
      u32 u = (m & 0x80000000u) ? (m & 0x7fffffffu) : ~m;     // un-orderable
      cand_vals[base + i] = __builtin_bit_cast(float, u);
      cand_idx[base + i] = (int)~(u32)H[i];
    }
  }
}

// ---------------- kernel 4: merge 256 chunk-lists -> approx top-32 -> fp32 rescore -> top-16 ----------------
#define POOL (NCH * TOPK)   // 4096
#define MSEL 32
__global__ __launch_bounds__(256) void merge_rescore_kernel(
    const float* __restrict__ cand_vals, const int* __restrict__ cand_idx,
    const float* __restrict__ qn, const float* __restrict__ e,
    const float* __restrict__ d, const float* __restrict__ inv_e,
    const float* __restrict__ inv_d, float* __restrict__ out) {
  __shared__ float mv[POOL];
  __shared__ int   mi[POOL];
  __shared__ float qf[DIM];
  __shared__ float wrv[4]; __shared__ int wri[4]; __shared__ int wrp[4];
  __shared__ float selv[MSEL]; __shared__ int seli[MSEL];
  __shared__ float fv[MSEL]; __shared__ int fi[MSEL];

  const int q = blockIdx.x, t = threadIdx.x;
  const int lane = t & 63, wave = t >> 6;

  #pragma unroll
  for (int j = 0; j < POOL / 256; j++) {
    int el = t + 256 * j;
    mv[el] = cand_vals[((size_t)(el >> 4) * BQ + q) * TOPK + (el & 15)];
    mi[el] = cand_idx[((size_t)(el >> 4) * BQ + q) * TOPK + (el & 15)];
  }
  if (t < 128) { qf[t] = qn[q * DIM + t]; qf[t + 128] = qn[q * DIM + t + 128]; qf[t + 256] = qn[q * DIM + t + 256]; }
  __syncthreads();

  // select approx top-32 (value desc, index asc)
  for (int pass = 0; pass < MSEL; pass++) {
    float bv = -INFINITY; int bi = 0x7fffffff, bp = 0;
    #pragma unroll
    for (int j = 0; j < POOL / 256; j++) {
      int el = t + 256 * j;
      float v = mv[el]; int ix = mi[el];
      if (v > bv || (v == bv && ix < bi)) { bv = v; bi = ix; bp = el; }
    }
    #pragma unroll
    for (int off = 1; off < 64; off <<= 1) {
      float ov = __shfl_xor(bv, off); int oi = __shfl_xor(bi, off); int op = __shfl_xor(bp, off);
      if (ov > bv || (ov == bv && oi < bi)) { bv = ov; bi = oi; bp = op; }
    }
    if (lane == 0) { wrv[wave] = bv; wri[wave] = bi; wrp[wave] = bp; }
    __syncthreads();
    if (t == 0) {
      float xv = wrv[0]; int xi = wri[0], xp = wrp[0];
      #pragma unroll
      for (int w = 1; w < 4; w++) {
        if (wrv[w] > xv || (wrv[w] == xv && wri[w] < xi)) { xv = wrv[w]; xi = wri[w]; xp = wrp[w]; }
      }
      selv[pass] = xv; seli[pass] = xi;
      mv[xp] = -INFINITY; mi[xp] = 0x7fffffff;
    }
    __syncthreads();
  }

  // exact fp32 rescore of the 32 candidates (same math as reference)
  for (int c = wave; c < MSEL; c += 4) {
    int idx = seli[c];
    const float* er = e + (size_t)idx * DIM;
    const float* dr = d + (size_t)idx * DIM;
    float se = 0.f, sd = 0.f;
    #pragma unroll
    for (int j = 0; j < 6; j++) {
      float qv = qf[j * 64 + lane];
      se += qv * er[j * 64 + lane];
      sd += qv * dr[j * 64 + lane];
    }
    #pragma unroll
    for (int off = 32; off; off >>= 1) { se += __shfl_xor(se, off); sd += __shfl_xor(sd, off); }
    if (lane == 0) {
      fv[c] = se * inv_e[idx] + ALPHA * fmaxf(sd * inv_d[idx], 0.f);
      fi[c] = idx;
    }
  }
  __syncthreads();

  // final exact top-16 (value desc, index asc), serial on t==0
  if (t == 0) {
    unsigned used = 0u;
    for (int p = 0; p < TOPK; p++) {
      float bv = -INFINITY; int bi = 0x7fffffff, bp = 0;
      for (int c = 0; c < MSEL; c++) {
        if (used & (1u << c)) continue;
        float v = fv[c]; int ix = fi[c];
        if (v > bv || (v == bv && ix < bi)) { bv = v; bi = ix; bp = c; }
      }
      used |= (1u << bp);
      out[q * TOPK + p] = bv;
      out[BQ * TOPK + q * TOPK + p] = (float)bi;
    }
  }
}

extern "C" void kernel_launch(void* const* d_in, const int* in_sizes, int n_in,
                              void* d_out, int out_size, void* d_ws, size_t ws_size,
                              hipStream_t stream) {
  const float* q = (const float*)d_in[0];
  const float* e = (const float*)d_in[1];
  const float* d = (const float*)d_in[2];

  float* ws = (float*)d_ws;
  float* qn        = ws;                                   // 1024*384
  float* inv_e     = qn + BQ * DIM;                        // 131072
  float* inv_d     = inv_e + NC;                           // 131072
  float* cand_vals = inv_d + NC;                           // 256*1024*16
  int*   cand_idx  = (int*)(cand_vals + (size_t)NCH * BQ * TOPK);
  ushort* qn16     = (ushort*)(cand_idx + (size_t)NCH * BQ * TOPK);   // 1024*384 bf16
  ushort* ed16     = qn16 + (size_t)BQ * DIM;                          // 2*NC*384 bf16 (201 MB)
  float* out = (float*)d_out;

  qnorm_kernel<<<BQ, 384, 0, stream>>>(q, qn, qn16);
  convert_kernel<<<NC * 2 / 4, 256, 0, stream>>>(e, d, inv_e, inv_d, ed16);
  score_kernel<<<NQT * NCH, 256, 0, stream>>>(ed16, qn16, inv_e, inv_d, cand_vals, cand_idx);
  merge_rescore_kernel<<<BQ, 256, 0, stream>>>(cand_vals, cand_idx, qn, e, d, inv_e, inv_d, out);
}